// Round 9
// baseline (144.222 us; speedup 1.0000x reference)
//
#include <hip/hip_runtime.h>

#define D 64
#define K 50
#define GROUPS 8              // 8 groups x 8 lanes; one neighbor row per group per iter
#define KPAD 56               // ceil(50/8)*8
#define ITERS (KPAD / GROUPS) // 7
#define RPB 16                // rows per block tile in phase B
#define THREADS 256
#define BLOCKS 1024           // guaranteed co-resident: launch_bounds caps VGPR<=128 -> 4 blk/CU

__device__ __forceinline__ float sb(unsigned v, int byte) {
    return (float)((int)(v << (24 - 8 * byte)) >> 24);   // sign-extend byte -> float
}

__global__ void zero_bar(unsigned long long* bar) { *bar = 0ull; }

__global__ __launch_bounds__(THREADS, 4)
void social_agg_fused(const int* __restrict__ nodes,
                      const int* __restrict__ u_u,
                      const float* __restrict__ deg,
                      const float* __restrict__ emb,
                      unsigned* __restrict__ emb8,
                      float* __restrict__ rtab,
                      float* __restrict__ wtab,
                      unsigned long long* bar,
                      float* __restrict__ out,
                      int batch, int nuser)
{
    // ---- phase A: per-row int8 quant of emb; rtab=rsqrt(deg); wtab=rtab*scale ----
    {
        const int items  = nuser * 16;                   // 16 lanes per row, float4/lane
        const int stride = gridDim.x * THREADS;
        for (int p = blockIdx.x * THREADS + threadIdx.x; p < items; p += stride) {
            const int row = p >> 4;
            const int sub = p & 15;
            const float4 f = ((const float4*)emb)[p];
            float m = fmaxf(fmaxf(fabsf(f.x), fabsf(f.y)),
                            fmaxf(fabsf(f.z), fabsf(f.w)));
            #pragma unroll
            for (int off = 1; off < 16; off <<= 1)
                m = fmaxf(m, __shfl_xor(m, off));        // rowmax in 16-lane group
            const float inv = (m > 0.0f) ? 127.0f / m : 0.0f;
            const int q0 = (int)rintf(f.x * inv);
            const int q1 = (int)rintf(f.y * inv);
            const int q2 = (int)rintf(f.z * inv);
            const int q3 = (int)rintf(f.w * inv);
            emb8[p] = (q0 & 0xFF) | ((q1 & 0xFF) << 8) | ((q2 & 0xFF) << 16) |
                      ((unsigned)(q3 & 0xFF) << 24);
            if (sub == 0) {
                const float n = deg[row];
                const float r = (n > 0.0f) ? rsqrtf(n) : 0.0f;
                rtab[row] = r;
                wtab[row] = r * m * (1.0f / 127.0f);     // rsqrt(deg)*scale in ONE table
            }
        }
    }

    // ---- manual grid barrier (release-arrive, acquire-spin; agent scope) ----
    __syncthreads();                                     // block's phase-A stores done
    if (threadIdx.x == 0) {
        __hip_atomic_fetch_add(bar, 1ull, __ATOMIC_RELEASE, __HIP_MEMORY_SCOPE_AGENT);
        const unsigned long long g = gridDim.x;
        int guard = 0;
        while (__hip_atomic_load(bar, __ATOMIC_ACQUIRE, __HIP_MEMORY_SCOPE_AGENT) < g) {
            __builtin_amdgcn_s_sleep(2);
            if (++guard > (1 << 22)) break;              // bail out instead of hanging
        }
    }
    __syncthreads();

    // ---- phase B: int8 gather; 8 lanes x 8 B per 64 B row; wave reduces 4 rows ----
    __shared__ uint2 nw[RPB][KPAD];                      // x = nb id, y = bitcast(w)
    for (int base = blockIdx.x * RPB; base < batch; base += gridDim.x * RPB) {
        for (int p = threadIdx.x; p < RPB * KPAD; p += THREADS) {
            const int r   = p / KPAD;
            const int k   = p - r * KPAD;
            const int row = base + r;
            int nb = 0; float w = 0.0f;
            if (row < batch && k < K) {
                const int node = nodes[row];
                nb = u_u[node * K + k];
                w  = rtab[node] * wtab[nb];              // 0 whenever a degree is 0
            }
            nw[r][k] = make_uint2((unsigned)nb, __float_as_uint(w));
        }
        __syncthreads();

        const int wave = threadIdx.x >> 6;
        const int lane = threadIdx.x & 63;
        const int g    = lane >> 3;                      // K-group 0..7
        const int sub  = lane & 7;                       // 8 B slice of 64 B row

        #pragma unroll
        for (int pair = 0; pair < 2; ++pair) {
            const int r0   = wave * 4 + pair * 2;        // this wave's row pair
            const int row0 = base + r0;
            float a0[8] = {0,0,0,0,0,0,0,0};
            float a1[8] = {0,0,0,0,0,0,0,0};
            #pragma unroll
            for (int i = 0; i < ITERS; ++i) {
                const uint2 e0 = nw[r0][i * GROUPS + g];
                const uint2 e1 = nw[r0 + 1][i * GROUPS + g];
                const float w0 = __uint_as_float(e0.y);
                const float w1 = __uint_as_float(e1.y);
                const uint2 v0 = *(const uint2*)(emb8 + (size_t)e0.x * (D/4) + sub*2);
                const uint2 v1 = *(const uint2*)(emb8 + (size_t)e1.x * (D/4) + sub*2);
                a0[0] += w0 * sb(v0.x, 0); a0[1] += w0 * sb(v0.x, 1);
                a0[2] += w0 * sb(v0.x, 2); a0[3] += w0 * sb(v0.x, 3);
                a0[4] += w0 * sb(v0.y, 0); a0[5] += w0 * sb(v0.y, 1);
                a0[6] += w0 * sb(v0.y, 2); a0[7] += w0 * sb(v0.y, 3);
                a1[0] += w1 * sb(v1.x, 0); a1[1] += w1 * sb(v1.x, 1);
                a1[2] += w1 * sb(v1.x, 2); a1[3] += w1 * sb(v1.x, 3);
                a1[4] += w1 * sb(v1.y, 0); a1[5] += w1 * sb(v1.y, 1);
                a1[6] += w1 * sb(v1.y, 2); a1[7] += w1 * sb(v1.y, 3);
            }
            #pragma unroll
            for (int off = 8; off <= 32; off <<= 1) {
                #pragma unroll
                for (int j = 0; j < 8; ++j) { a0[j] += __shfl_xor(a0[j], off);
                                              a1[j] += __shfl_xor(a1[j], off); }
            }
            if (g == 0) {
                if (row0 < batch) {
                    float* o = out + (size_t)row0 * D + sub * 8;
                    *(float4*)(o)     = make_float4(a0[0], a0[1], a0[2], a0[3]);
                    *(float4*)(o + 4) = make_float4(a0[4], a0[5], a0[6], a0[7]);
                }
                if (row0 + 1 < batch) {
                    float* o = out + (size_t)(row0 + 1) * D + sub * 8;
                    *(float4*)(o)     = make_float4(a1[0], a1[1], a1[2], a1[3]);
                    *(float4*)(o + 4) = make_float4(a1[4], a1[5], a1[6], a1[7]);
                }
            }
        }
        __syncthreads();                                 // before LDS reuse
    }
}

// ---------- fallback (fp32 single-kernel) if workspace is too small ----------
__global__ __launch_bounds__(THREADS)
void social_agg_f32(const int* __restrict__ nodes,
                    const int* __restrict__ u_u,
                    const float* __restrict__ u_u_l,
                    const float* __restrict__ emb,
                    float* __restrict__ out,
                    int batch)
{
    __shared__ uint2 nw[4][52];
    const int base = blockIdx.x * 4;
    const int p = threadIdx.x;
    if (p < 4 * 52) {
        const int r = p / 52, k = p - r * 52, row = base + r;
        int nb = 0; float w = 0.0f;
        if (row < batch && k < K) {
            const int node = nodes[row];
            const float Na = u_u_l[node];
            nb = u_u[node * K + k];
            const float prod = Na * u_u_l[nb];
            w = (prod > 0.0f) ? rsqrtf(prod) : 0.0f;
        }
        nw[r][k] = make_uint2((unsigned)nb, __float_as_uint(w));
    }
    __syncthreads();
    const int wave = threadIdx.x >> 6, lane = threadIdx.x & 63;
    const int kk = lane >> 4, sub = lane & 15, row = base + wave;
    float4 acc = make_float4(0.f, 0.f, 0.f, 0.f);
    #pragma unroll
    for (int i = 0; i < 13; ++i) {
        const uint2 e = nw[wave][i * 4 + kk];
        const float wk = __uint_as_float(e.y);
        const float4 v = *(const float4*)(emb + (size_t)e.x * D + sub * 4);
        acc.x += wk * v.x; acc.y += wk * v.y; acc.z += wk * v.z; acc.w += wk * v.w;
    }
    #pragma unroll
    for (int off = 16; off <= 32; off <<= 1) {
        acc.x += __shfl_xor(acc.x, off);
        acc.y += __shfl_xor(acc.y, off);
        acc.z += __shfl_xor(acc.z, off);
        acc.w += __shfl_xor(acc.w, off);
    }
    if (row < batch && kk == 0)
        *(float4*)(out + (size_t)row * D + sub * 4) = acc;
}

extern "C" void kernel_launch(void* const* d_in, const int* in_sizes, int n_in,
                              void* d_out, int out_size, void* d_ws, size_t ws_size,
                              hipStream_t stream) {
    const int*   nodes = (const int*)d_in[0];
    const int*   u_u   = (const int*)d_in[1];
    const float* u_u_l = (const float*)d_in[2];
    const float* emb   = (const float*)d_in[3];
    float*       out   = (float*)d_out;

    int batch = in_sizes[0];
    int nuser = in_sizes[1] / K;                         // N_USERS

    const size_t emb8_bytes = (size_t)nuser * D;         // int8 table (64 B/row)
    const size_t tab_bytes  = (size_t)nuser * 4;
    const size_t bar_off    = emb8_bytes + 2 * tab_bytes;
    if (ws_size >= bar_off + 8) {
        unsigned*           emb8 = (unsigned*)d_ws;
        float*              rtab = (float*)((char*)d_ws + emb8_bytes);
        float*              wtab = (float*)((char*)d_ws + emb8_bytes + tab_bytes);
        unsigned long long* bar  = (unsigned long long*)((char*)d_ws + bar_off);
        zero_bar<<<1, 1, 0, stream>>>(bar);
        social_agg_fused<<<BLOCKS, THREADS, 0, stream>>>(nodes, u_u, u_u_l, emb,
                                                         emb8, rtab, wtab, bar,
                                                         out, batch, nuser);
    } else {
        const int blocks = (batch + 3) / 4;
        social_agg_f32<<<blocks, THREADS, 0, stream>>>(nodes, u_u, u_u_l, emb,
                                                       out, batch);
    }
}

// Round 10
// 133.941 us; speedup vs baseline: 1.0768x; 1.0768x over previous
//
#include <hip/hip_runtime.h>

#define D 64
#define K 50
#define GROUPS 8              // 8 groups x 8 lanes; one neighbor row per group per iter
#define KPAD 56               // ceil(50/8)*8
#define ITERS (KPAD / GROUPS) // 7
#define RPB 16                // rows per block tile in phase B
#define THREADS 256
#define BLOCKS 1024           // co-resident: launch_bounds(256,4) -> 4 blk/CU x 256 CU

__device__ __forceinline__ float sb(unsigned v, int byte) {
    return (float)((int)(v << (24 - 8 * byte)) >> 24);   // sign-extend byte -> float
}

__global__ void zero_bar(unsigned* bar) { bar[0] = 0u; bar[1] = 0u; }

__global__ __launch_bounds__(THREADS, 4)
void social_agg_fused(const int* __restrict__ nodes,
                      const int* __restrict__ u_u,
                      const float* __restrict__ deg,
                      const float* __restrict__ emb,
                      unsigned* __restrict__ emb8,
                      float* __restrict__ rtab,
                      float* __restrict__ wtab,
                      unsigned* __restrict__ bar,   // bar[0]=arrive cnt, bar[1]=go flag
                      float* __restrict__ out,
                      int batch, int nuser)
{
    // ---- phase A: per-row int8 quant of emb; rtab=rsqrt(deg); wtab=rtab*scale ----
    {
        const int items  = nuser * 16;                   // 16 lanes per row, float4/lane
        const int stride = gridDim.x * THREADS;
        for (int p = blockIdx.x * THREADS + threadIdx.x; p < items; p += stride) {
            const int row = p >> 4;
            const int sub = p & 15;
            const float4 f = ((const float4*)emb)[p];
            float m = fmaxf(fmaxf(fabsf(f.x), fabsf(f.y)),
                            fmaxf(fabsf(f.z), fabsf(f.w)));
            #pragma unroll
            for (int off = 1; off < 16; off <<= 1)
                m = fmaxf(m, __shfl_xor(m, off));        // rowmax in 16-lane group
            const float inv = (m > 0.0f) ? 127.0f / m : 0.0f;
            const int q0 = (int)rintf(f.x * inv);
            const int q1 = (int)rintf(f.y * inv);
            const int q2 = (int)rintf(f.z * inv);
            const int q3 = (int)rintf(f.w * inv);
            emb8[p] = (q0 & 0xFF) | ((q1 & 0xFF) << 8) | ((q2 & 0xFF) << 16) |
                      ((unsigned)(q3 & 0xFF) << 24);
            if (sub == 0) {
                const float n = deg[row];
                const float r = (n > 0.0f) ? rsqrtf(n) : 0.0f;
                rtab[row] = r;
                wtab[row] = r * m * (1.0f / 127.0f);     // rsqrt(deg)*scale in ONE table
            }
        }
    }

    // ---- grid barrier: count arrivals; LAST arriver sets go; others spin slowly ----
    __syncthreads();                                     // block's phase-A stores issued
    if (threadIdx.x == 0) {
        const unsigned old = __hip_atomic_fetch_add(&bar[0], 1u, __ATOMIC_ACQ_REL,
                                                    __HIP_MEMORY_SCOPE_AGENT);
        if (old == gridDim.x - 1) {
            __hip_atomic_store(&bar[1], 1u, __ATOMIC_RELEASE,
                               __HIP_MEMORY_SCOPE_AGENT);
        } else {
            int guard = 0;
            while (__hip_atomic_load(&bar[1], __ATOMIC_ACQUIRE,
                                     __HIP_MEMORY_SCOPE_AGENT) == 0u) {
                __builtin_amdgcn_s_sleep(48);            // ~1.3 us between probes
                if (++guard > (1 << 14)) break;          // bail instead of hanging
            }
        }
    }
    __syncthreads();

    // ---- phase B: int8 gather; 8 lanes x 8 B per 64 B row; wave reduces 4 rows ----
    __shared__ uint2 nw[RPB][KPAD];                      // x = nb id, y = bitcast(w)
    for (int base = blockIdx.x * RPB; base < batch; base += gridDim.x * RPB) {
        for (int p = threadIdx.x; p < RPB * KPAD; p += THREADS) {
            const int r   = p / KPAD;
            const int k   = p - r * KPAD;
            const int row = base + r;
            int nb = 0; float w = 0.0f;
            if (row < batch && k < K) {
                const int node = nodes[row];
                nb = u_u[node * K + k];
                w  = rtab[node] * wtab[nb];              // 0 whenever a degree is 0
            }
            nw[r][k] = make_uint2((unsigned)nb, __float_as_uint(w));
        }
        __syncthreads();

        const int wave = threadIdx.x >> 6;
        const int lane = threadIdx.x & 63;
        const int g    = lane >> 3;                      // K-group 0..7
        const int sub  = lane & 7;                       // 8 B slice of 64 B row

        #pragma unroll
        for (int pair = 0; pair < 2; ++pair) {
            const int r0   = wave * 4 + pair * 2;        // this wave's row pair
            const int row0 = base + r0;
            float a0[8] = {0,0,0,0,0,0,0,0};
            float a1[8] = {0,0,0,0,0,0,0,0};
            #pragma unroll
            for (int i = 0; i < ITERS; ++i) {
                const uint2 e0 = nw[r0][i * GROUPS + g];
                const uint2 e1 = nw[r0 + 1][i * GROUPS + g];
                const float w0 = __uint_as_float(e0.y);
                const float w1 = __uint_as_float(e1.y);
                const uint2 v0 = *(const uint2*)(emb8 + (size_t)e0.x * (D/4) + sub*2);
                const uint2 v1 = *(const uint2*)(emb8 + (size_t)e1.x * (D/4) + sub*2);
                a0[0] += w0 * sb(v0.x, 0); a0[1] += w0 * sb(v0.x, 1);
                a0[2] += w0 * sb(v0.x, 2); a0[3] += w0 * sb(v0.x, 3);
                a0[4] += w0 * sb(v0.y, 0); a0[5] += w0 * sb(v0.y, 1);
                a0[6] += w0 * sb(v0.y, 2); a0[7] += w0 * sb(v0.y, 3);
                a1[0] += w1 * sb(v1.x, 0); a1[1] += w1 * sb(v1.x, 1);
                a1[2] += w1 * sb(v1.x, 2); a1[3] += w1 * sb(v1.x, 3);
                a1[4] += w1 * sb(v1.y, 0); a1[5] += w1 * sb(v1.y, 1);
                a1[6] += w1 * sb(v1.y, 2); a1[7] += w1 * sb(v1.y, 3);
            }
            #pragma unroll
            for (int off = 8; off <= 32; off <<= 1) {
                #pragma unroll
                for (int j = 0; j < 8; ++j) { a0[j] += __shfl_xor(a0[j], off);
                                              a1[j] += __shfl_xor(a1[j], off); }
            }
            if (g == 0) {
                if (row0 < batch) {
                    float* o = out + (size_t)row0 * D + sub * 8;
                    *(float4*)(o)     = make_float4(a0[0], a0[1], a0[2], a0[3]);
                    *(float4*)(o + 4) = make_float4(a0[4], a0[5], a0[6], a0[7]);
                }
                if (row0 + 1 < batch) {
                    float* o = out + (size_t)(row0 + 1) * D + sub * 8;
                    *(float4*)(o)     = make_float4(a1[0], a1[1], a1[2], a1[3]);
                    *(float4*)(o + 4) = make_float4(a1[4], a1[5], a1[6], a1[7]);
                }
            }
        }
        __syncthreads();                                 // before LDS reuse
    }
}

// ---------- fallback (fp32 single-kernel) if workspace is too small ----------
__global__ __launch_bounds__(THREADS)
void social_agg_f32(const int* __restrict__ nodes,
                    const int* __restrict__ u_u,
                    const float* __restrict__ u_u_l,
                    const float* __restrict__ emb,
                    float* __restrict__ out,
                    int batch)
{
    __shared__ uint2 nw[4][52];
    const int base = blockIdx.x * 4;
    const int p = threadIdx.x;
    if (p < 4 * 52) {
        const int r = p / 52, k = p - r * 52, row = base + r;
        int nb = 0; float w = 0.0f;
        if (row < batch && k < K) {
            const int node = nodes[row];
            const float Na = u_u_l[node];
            nb = u_u[node * K + k];
            const float prod = Na * u_u_l[nb];
            w = (prod > 0.0f) ? rsqrtf(prod) : 0.0f;
        }
        nw[r][k] = make_uint2((unsigned)nb, __float_as_uint(w));
    }
    __syncthreads();
    const int wave = threadIdx.x >> 6, lane = threadIdx.x & 63;
    const int kk = lane >> 4, sub = lane & 15, row = base + wave;
    float4 acc = make_float4(0.f, 0.f, 0.f, 0.f);
    #pragma unroll
    for (int i = 0; i < 13; ++i) {
        const uint2 e = nw[wave][i * 4 + kk];
        const float wk = __uint_as_float(e.y);
        const float4 v = *(const float4*)(emb + (size_t)e.x * D + sub * 4);
        acc.x += wk * v.x; acc.y += wk * v.y; acc.z += wk * v.z; acc.w += wk * v.w;
    }
    #pragma unroll
    for (int off = 16; off <= 32; off <<= 1) {
        acc.x += __shfl_xor(acc.x, off);
        acc.y += __shfl_xor(acc.y, off);
        acc.z += __shfl_xor(acc.z, off);
        acc.w += __shfl_xor(acc.w, off);
    }
    if (row < batch && kk == 0)
        *(float4*)(out + (size_t)row * D + sub * 4) = acc;
}

extern "C" void kernel_launch(void* const* d_in, const int* in_sizes, int n_in,
                              void* d_out, int out_size, void* d_ws, size_t ws_size,
                              hipStream_t stream) {
    const int*   nodes = (const int*)d_in[0];
    const int*   u_u   = (const int*)d_in[1];
    const float* u_u_l = (const float*)d_in[2];
    const float* emb   = (const float*)d_in[3];
    float*       out   = (float*)d_out;

    int batch = in_sizes[0];
    int nuser = in_sizes[1] / K;                         // N_USERS

    const size_t emb8_bytes = (size_t)nuser * D;         // int8 table (64 B/row)
    const size_t tab_bytes  = (size_t)nuser * 4;
    const size_t bar_off    = emb8_bytes + 2 * tab_bytes;
    if (ws_size >= bar_off + 2 * sizeof(unsigned)) {
        unsigned* emb8 = (unsigned*)d_ws;
        float*    rtab = (float*)((char*)d_ws + emb8_bytes);
        float*    wtab = (float*)((char*)d_ws + emb8_bytes + tab_bytes);
        unsigned* bar  = (unsigned*)((char*)d_ws + bar_off);
        zero_bar<<<1, 1, 0, stream>>>(bar);
        social_agg_fused<<<BLOCKS, THREADS, 0, stream>>>(nodes, u_u, u_u_l, emb,
                                                         emb8, rtab, wtab, bar,
                                                         out, batch, nuser);
    } else {
        const int blocks = (batch + 3) / 4;
        social_agg_f32<<<blocks, THREADS, 0, stream>>>(nodes, u_u, u_u_l, emb,
                                                       out, batch);
    }
}

// Round 12
// 29.149 us; speedup vs baseline: 4.9478x; 4.5951x over previous
//
#include <hip/hip_runtime.h>

#define D 64
#define K 50
#define GROUPS 8               // 8 groups x 8 lanes; one neighbor row per group per iter
#define KPAD 56                // ceil(50/8)*8
#define ITERS (KPAD / GROUPS)  // 7
#define RPB 8                  // rows per block; each of 4 waves reduces 2 rows
#define THREADS 256
#define ROW_BYTES 72           // 64 B int8 + 4 B combined factor + 4 B pad

// ---------- prologue: per-row int8 quant; factor = rsqrt(deg)*rowmax/127 embedded in row
__global__ __launch_bounds__(THREADS)
void prep_q8(const float* __restrict__ emb, const float* __restrict__ deg,
             char* __restrict__ tab, float* __restrict__ rtab, int nuser)
{
    const int tid = blockIdx.x * THREADS + threadIdx.x;
    const int row = tid >> 4;
    const int sub = tid & 15;

    // zero the sentinel row (id == nuser): 18 uints = 72 B
    if (blockIdx.x == 0 && threadIdx.x < ROW_BYTES / 4)
        ((unsigned*)(tab + (size_t)nuser * ROW_BYTES))[threadIdx.x] = 0u;

    if (row >= nuser) return;

    const float4 f = ((const float4*)emb)[row * 16 + sub];
    float m = fmaxf(fmaxf(fabsf(f.x), fabsf(f.y)), fmaxf(fabsf(f.z), fabsf(f.w)));
    #pragma unroll
    for (int off = 1; off < 16; off <<= 1)
        m = fmaxf(m, __shfl_xor(m, off));            // rowmax within 16-lane group
    const float inv = (m > 0.0f) ? 127.0f / m : 0.0f;
    const int q0 = (int)rintf(f.x * inv);
    const int q1 = (int)rintf(f.y * inv);
    const int q2 = (int)rintf(f.z * inv);
    const int q3 = (int)rintf(f.w * inv);
    const unsigned pk = (q0 & 0xFF) | ((q1 & 0xFF) << 8) |
                        ((q2 & 0xFF) << 16) | ((unsigned)(q3 & 0xFF) << 24);
    char* rbase = tab + (size_t)row * ROW_BYTES;
    *(unsigned*)(rbase + sub * 4) = pk;              // 64 B of int8
    if (sub == 0) {
        const float n = deg[row];
        const float r = (n > 0.0f) ? rsqrtf(n) : 0.0f;
        rtab[row] = r;
        *(float*)(rbase + 64) = r * m * (1.0f / 127.0f);  // neighbor-side factor in-row
    }
}

__device__ __forceinline__ float sb(unsigned v, int byte) {
    return (float)((int)(v << (24 - 8 * byte)) >> 24);   // sign-extend byte -> float
}

// ---------- main: phase 1 = coalesced u_u only (no random table gather);
// ---------- phase 2 = 72 B row gather (int8 data + in-row factor)
__global__ __launch_bounds__(THREADS)
void social_agg_q8(const int* __restrict__ nodes,
                   const int* __restrict__ u_u,
                   const float* __restrict__ rtab,
                   const char* __restrict__ tab,
                   float* __restrict__ out,
                   int batch, int nuser)
{
    __shared__ unsigned ids[RPB][KPAD];
    __shared__ float    cfac[RPB];                   // rtab[center node] per row
    const int base = blockIdx.x * RPB;

    // STRIDED loop: RPB*KPAD = 448 slots > 256 threads (R11 bug was a single pass)
    for (int p = threadIdx.x; p < RPB * KPAD; p += THREADS) {
        const int r   = p / KPAD;
        const int k   = p - r * KPAD;
        const int row = base + r;
        unsigned nb = (unsigned)nuser;               // sentinel: zero row, factor 0
        if (row < batch && k < K)
            nb = (unsigned)u_u[nodes[row] * K + k];  // coalesced in k
        ids[r][k] = nb;
    }
    if (threadIdx.x < RPB) {
        const int row = base + threadIdx.x;
        cfac[threadIdx.x] = (row < batch) ? rtab[nodes[row]] : 0.0f;
    }
    __syncthreads();

    const int wave = threadIdx.x >> 6;
    const int lane = threadIdx.x & 63;
    const int g    = lane >> 3;                      // K-group 0..7
    const int sub  = lane & 7;                       // 8 B slice of the 64 B int8 data
    const int r0   = wave * 2;
    const int row0 = base + r0;

    float a0[8] = {0,0,0,0,0,0,0,0};
    float a1[8] = {0,0,0,0,0,0,0,0};
    #pragma unroll
    for (int i = 0; i < ITERS; ++i) {
        const unsigned nb0 = ids[r0][i * GROUPS + g];
        const unsigned nb1 = ids[r0 + 1][i * GROUPS + g];
        const char* b0 = tab + (size_t)nb0 * ROW_BYTES;
        const char* b1 = tab + (size_t)nb1 * ROW_BYTES;
        const uint2 v0 = *(const uint2*)(b0 + sub * 8);
        const uint2 v1 = *(const uint2*)(b1 + sub * 8);
        const float f0 = *(const float*)(b0 + 64);   // same lines as row data
        const float f1 = *(const float*)(b1 + 64);
        a0[0] += f0 * sb(v0.x, 0); a0[1] += f0 * sb(v0.x, 1);
        a0[2] += f0 * sb(v0.x, 2); a0[3] += f0 * sb(v0.x, 3);
        a0[4] += f0 * sb(v0.y, 0); a0[5] += f0 * sb(v0.y, 1);
        a0[6] += f0 * sb(v0.y, 2); a0[7] += f0 * sb(v0.y, 3);
        a1[0] += f1 * sb(v1.x, 0); a1[1] += f1 * sb(v1.x, 1);
        a1[2] += f1 * sb(v1.x, 2); a1[3] += f1 * sb(v1.x, 3);
        a1[4] += f1 * sb(v1.y, 0); a1[5] += f1 * sb(v1.y, 1);
        a1[6] += f1 * sb(v1.y, 2); a1[7] += f1 * sb(v1.y, 3);
    }

    #pragma unroll
    for (int off = 8; off <= 32; off <<= 1) {
        #pragma unroll
        for (int j = 0; j < 8; ++j) { a0[j] += __shfl_xor(a0[j], off);
                                      a1[j] += __shfl_xor(a1[j], off); }
    }

    if (g == 0) {
        if (row0 < batch) {
            const float c = cfac[r0];
            float* o = out + (size_t)row0 * D + sub * 8;
            *(float4*)(o)     = make_float4(c*a0[0], c*a0[1], c*a0[2], c*a0[3]);
            *(float4*)(o + 4) = make_float4(c*a0[4], c*a0[5], c*a0[6], c*a0[7]);
        }
        if (row0 + 1 < batch) {
            const float c = cfac[r0 + 1];
            float* o = out + (size_t)(row0 + 1) * D + sub * 8;
            *(float4*)(o)     = make_float4(c*a1[0], c*a1[1], c*a1[2], c*a1[3]);
            *(float4*)(o + 4) = make_float4(c*a1[4], c*a1[5], c*a1[6], c*a1[7]);
        }
    }
}

// ---------- fallback (fp32 single-kernel) if workspace is too small ----------
__global__ __launch_bounds__(THREADS)
void social_agg_f32(const int* __restrict__ nodes,
                    const int* __restrict__ u_u,
                    const float* __restrict__ u_u_l,
                    const float* __restrict__ emb,
                    float* __restrict__ out,
                    int batch)
{
    __shared__ uint2 nw[4][52];
    const int base = blockIdx.x * 4;
    const int p = threadIdx.x;
    if (p < 4 * 52) {
        const int r = p / 52, k = p - r * 52, row = base + r;
        int nb = 0; float w = 0.0f;
        if (row < batch && k < K) {
            const int node = nodes[row];
            const float Na = u_u_l[node];
            nb = u_u[node * K + k];
            const float prod = Na * u_u_l[nb];
            w = (prod > 0.0f) ? rsqrtf(prod) : 0.0f;
        }
        nw[r][k] = make_uint2((unsigned)nb, __float_as_uint(w));
    }
    __syncthreads();
    const int wave = threadIdx.x >> 6, lane = threadIdx.x & 63;
    const int kk = lane >> 4, sub = lane & 15, row = base + wave;
    float4 acc = make_float4(0.f, 0.f, 0.f, 0.f);
    #pragma unroll
    for (int i = 0; i < 13; ++i) {
        const uint2 e = nw[wave][i * 4 + kk];
        const float wk = __uint_as_float(e.y);
        const float4 v = *(const float4*)(emb + (size_t)e.x * D + sub * 4);
        acc.x += wk * v.x; acc.y += wk * v.y; acc.z += wk * v.z; acc.w += wk * v.w;
    }
    #pragma unroll
    for (int off = 16; off <= 32; off <<= 1) {
        acc.x += __shfl_xor(acc.x, off);
        acc.y += __shfl_xor(acc.y, off);
        acc.z += __shfl_xor(acc.z, off);
        acc.w += __shfl_xor(acc.w, off);
    }
    if (row < batch && kk == 0)
        *(float4*)(out + (size_t)row * D + sub * 4) = acc;
}

extern "C" void kernel_launch(void* const* d_in, const int* in_sizes, int n_in,
                              void* d_out, int out_size, void* d_ws, size_t ws_size,
                              hipStream_t stream) {
    const int*   nodes = (const int*)d_in[0];
    const int*   u_u   = (const int*)d_in[1];
    const float* u_u_l = (const float*)d_in[2];
    const float* emb   = (const float*)d_in[3];
    float*       out   = (float*)d_out;

    const int batch = in_sizes[0];
    const int nuser = in_sizes[1] / K;                   // N_USERS

    const size_t tab_bytes  = (size_t)(nuser + 1) * ROW_BYTES;  // +1 sentinel row
    const size_t rtab_bytes = (size_t)nuser * 4;
    if (ws_size >= tab_bytes + rtab_bytes) {
        char*  tab  = (char*)d_ws;
        float* rtab = (float*)((char*)d_ws + tab_bytes);
        const int pthreads = nuser * 16;                 // 16 lanes per row
        const int pblocks  = (pthreads + THREADS - 1) / THREADS;
        prep_q8<<<pblocks, THREADS, 0, stream>>>(emb, u_u_l, tab, rtab, nuser);
        const int blocks = (batch + RPB - 1) / RPB;
        social_agg_q8<<<blocks, THREADS, 0, stream>>>(nodes, u_u, rtab, tab,
                                                      out, batch, nuser);
    } else {
        const int blocks = (batch + 3) / 4;
        social_agg_f32<<<blocks, THREADS, 0, stream>>>(nodes, u_u, u_u_l, emb,
                                                       out, batch);
    }
}